// Round 1
// 668.185 us; speedup vs baseline: 1.1075x; 1.1075x over previous
//
#include <hip/hip_runtime.h>

// Slater-determinant ordered sampler, D=512 sites, N=128 particles.
//
// N x N inverse-block recursion (det(I-UU^T) = det(I-U^T U)):
//   A_0 = I_N;  per site i with p = P[i,:]:
//     w = A p;  s = 1 - p.w   (== reference Schur pivot s_i)
//     <decision logic identical to reference>
//     A += w w^T / pivot,  pivot = s - occupy
// State A (128x128 fp32) in registers of one 512-thread workgroup:
//   wave v (of 8) owns cols [16v,16v+16); lane l owns rows {l, l+64}.
//
// This revision removes LDS-pipe pressure (the measured bottleneck: ~1700
// LDS-pipe cycles/iter across 8 waves on one CU):
//   - wave-uniform broadcasts (p fragments, w columns, u_k) via v_readlane
//     (VALU/SALU crossbar) instead of ds_bpermute / LDS broadcast reads
//   - 64-lane butterfly via permlane32_swap/permlane16_swap/DPP (VALU) with
//     exact xor partners -> bitwise-identical sums (fp add is commutative;
//     only associativity/pairing would change rounding, and pairing is kept)
//   - P rows live in registers (double-buffered), not LDS
// Only remaining LDS per iter: matvec partial write + 8 reads + one
// ds_swizzle (^4 stage, no DPP pattern exists for lane^4).

#define DD 512
#define NN 128
#define NTHREADS 512

__device__ __forceinline__ float lane_bcast(float v, int l) {
  // l is wave-uniform -> v_readlane_b32 (no LDS traffic), value bit-exact.
  return __int_as_float(__builtin_amdgcn_readlane(__float_as_int(v), l));
}

__device__ __forceinline__ float wave_reduce_add64(float sd) {
  // Bitwise-identical to: for off in {32,16,8,4,2,1} sd += __shfl_xor(sd,off,64)
  // (each stage adds the exact xor-partner's value; operand order commutes).
#if __has_builtin(__builtin_amdgcn_permlane32_swap)
  {
    unsigned xi = __float_as_uint(sd);
    auto r = __builtin_amdgcn_permlane32_swap(xi, xi, false, false);
    sd = __uint_as_float(r[0]) + __uint_as_float(r[1]);  // = x[l] + x[l^32]
  }
#else
  sd += __shfl_xor(sd, 32, 64);
#endif
#if __has_builtin(__builtin_amdgcn_permlane16_swap)
  {
    unsigned xi = __float_as_uint(sd);
    auto r = __builtin_amdgcn_permlane16_swap(xi, xi, false, false);
    sd = __uint_as_float(r[0]) + __uint_as_float(r[1]);  // = x[l] + x[l^16]
  }
#else
  sd += __shfl_xor(sd, 16, 64);
#endif
  // row_ror:8 within row-of-16 == exact lane^8 partner (VALU DPP)
  sd += __int_as_float(
      __builtin_amdgcn_update_dpp(0, __float_as_int(sd), 0x128, 0xF, 0xF, true));
  // lane^4: no DPP pattern -> one ds_swizzle (BitMode xor=4)
  sd += __int_as_float(
      __builtin_amdgcn_ds_swizzle(__float_as_int(sd), 0x101F));
  // quad_perm [2,3,0,1] == lane^2
  sd += __int_as_float(
      __builtin_amdgcn_update_dpp(0, __float_as_int(sd), 0x4E, 0xF, 0xF, true));
  // quad_perm [1,0,3,2] == lane^1
  sd += __int_as_float(
      __builtin_amdgcn_update_dpp(0, __float_as_int(sd), 0xB1, 0xF, 0xF, true));
  return sd;
}

__global__ __launch_bounds__(NTHREADS) void slater_scan_kernel(
    const float* __restrict__ P, const float* __restrict__ u,
    float* __restrict__ out) {
  const int tid   = threadIdx.x;
  const int wave  = tid >> 6;
  const int lane  = tid & 63;
  const int c0    = wave << 4;   // first column owned by this wave
  const int rbase = c0 & 63;     // readlane base within the half
  const bool lowhalf = (wave < 4);  // cols 0-63 come from the low-row regs

  __shared__ float2 part[2][8][64];  // per-wave matvec partials (double buf)

  // Zero cond_probs region (harness poisons d_out with 0xAA).
  for (int j = tid; j < NN * DD; j += NTHREADS) out[j] = 0.0f;

  // u and P row 0 into registers: lane holds entries {lane, lane+64}.
  const float ur0 = u[lane];
  const float ur1 = u[64 + lane];
  float p0 = P[lane];        // p_i[lane]
  float p1 = P[64 + lane];   // p_i[lane+64]

  // A = I_N distributed into registers.
  float A0[16], A1[16];
#pragma unroll
  for (int j = 0; j < 16; ++j) {
    A0[j] = (lane == c0 + j) ? 1.0f : 0.0f;
    A1[j] = (lane + 64 == c0 + j) ? 1.0f : 0.0f;
  }

  // Decision state, replicated bit-identically in every thread.
  float ratio = 1.0f, cumul = 0.0f;
  int k = 0;

  __syncthreads();  // out-zeroing ordered before tid0's in-loop out writes

  for (int i = 0; i < DD; ++i) {
    const int buf = i & 1;

    // Early-issue next P row load (register double buffer, L1-resident).
    float pn0 = 0.0f, pn1 = 0.0f;
    if (i + 1 < DD) {
      pn0 = P[(i + 1) * NN + lane];
      pn1 = P[(i + 1) * NN + 64 + lane];
    }

    // u_k for the current k (uniform), from registers — no LDS.
    const int kidx = (k < NN) ? k : (NN - 1);
    const float uk_l = lane_bcast(ur0, kidx & 63);
    const float uk_h = lane_bcast(ur1, kidx & 63);
    const float uk = (kidx < 64) ? uk_l : uk_h;

    // Partial matvec over this wave's 16 columns; p values via readlane
    // (bit-exact same values the old LDS pbuf reads produced, same order).
    const float psrc = lowhalf ? p0 : p1;
    float pa0 = 0.0f, pa1 = 0.0f;
#pragma unroll
    for (int j = 0; j < 16; ++j) {
      const float pcj = lane_bcast(psrc, rbase + j);
      pa0 = fmaf(A0[j], pcj, pa0);
      pa1 = fmaf(A1[j], pcj, pa1);
    }
    part[buf][wave][lane] = make_float2(pa0, pa1);
    __syncthreads();  // the only barrier per step

    // w for this lane's two rows (sum of 8 wave partials, fixed order v=0..7
    // -> bit-identical in every wave).
    float wl = 0.0f, wh = 0.0f;
#pragma unroll
    for (int v = 0; v < 8; ++v) {
      const float2 t = part[buf][v][lane];
      wl += t.x;
      wh += t.y;
    }

    // s = 1 - p.w, reduced redundantly per wave (stage order 32..1 kept).
    float sd = fmaf(p0, wl, p1 * wh);
    sd = wave_reduce_add64(sd);
    const float s = 1.0f - sd;

    // Decision logic — mirrors the reference exactly.
    const int last_allowed = DD - NN + k;
    const bool active = (k < NN) && (i <= last_allowed);
    const float pr = active ? (-(s - 1.0f) * ratio) : 0.0f;
    const bool occupy = active && ((cumul + pr >= uk) || (i == last_allowed));
    float pivot = occupy ? (s - 1.0f) : s;
    pivot = (fabsf(pivot) < 1e-30f) ? 1e-30f : pivot;
    const float invp = 1.0f / pivot;

    if (tid == 0) {
      if (k < NN) out[k * DD + i] = pr;         // cond_probs[k, i]
      if (occupy) out[NN * DD + k] = (float)i;  // positions[k]
    }

    ratio = occupy ? 1.0f : (active ? ratio * s : ratio);
    cumul = occupy ? 0.0f : (cumul + pr);
    k += occupy ? 1 : 0;

    if (k == NN) break;  // uniform across all threads; outputs complete

    // Rank-1 update: A[r,c] += w[r] * w[c] / pivot.
    // w[c] fetched via readlane (wave-uniform lane) instead of ds_bpermute.
    const float wsrc = lowhalf ? wl : wh;
#pragma unroll
    for (int j = 0; j < 16; ++j) {
      const float wc = lane_bcast(wsrc, rbase + j);
      const float t = wc * invp;
      A0[j] = fmaf(wl, t, A0[j]);
      A1[j] = fmaf(wh, t, A1[j]);
    }

    p0 = pn0;
    p1 = pn1;
  }
}

extern "C" void kernel_launch(void* const* d_in, const int* in_sizes, int n_in,
                              void* d_out, int out_size, void* d_ws,
                              size_t ws_size, hipStream_t stream) {
  const float* P = (const float*)d_in[0];  // (512, 128) row-major fp32
  const float* u = (const float*)d_in[1];  // (128,) fp32
  float* out = (float*)d_out;              // 65536 cond_probs + 128 positions
  hipLaunchKernelGGL(slater_scan_kernel, dim3(1), dim3(NTHREADS), 0, stream,
                     P, u, out);
}

// Round 2
// 488.035 us; speedup vs baseline: 1.5163x; 1.3691x over previous
//
#include <hip/hip_runtime.h>

// Slater-determinant ordered sampler, D=512 sites, N=128 particles.
//
// Blocked (B=16) form of the verified N x N recursion:
//   per site: w = A p;  s = 1 - p.w;  <decision>;  A += w w^T / pivot.
// Exact left-looking identity (A symmetric throughout):
//   V = A0 P_B^T                         (heavy, parallel)
//   C = P_B V = P_B A0 P_B^T             (16x16, symmetric)
//   scan on C only:  D[j][t] = C[j][t] + sum_{l<j} f_lj D[l][t],
//                    f_jt = D[j][t]/pivot_j,
//                    s_t  = 1 - (C[t][t] + sum_{j<t} D[j][t]^2/pivot_j)
//   w_t = V_t + sum_{j<t} f_jt w_j       (fused into scan)
//   A  += W diag(1/pivot) W^T            (rank-16, parallel)
// This replaces 512 barrier-synchronized rounds (the measured bottleneck:
// ~3100 cyc/site vs ~600 issue) with 32 blocks x 3 barriers.
//
// Layout: wave v (of 8) owns A cols [16v,16v+16); lane l owns rows {l,l+64}.
// All wave-uniform broadcasts via v_readlane; butterfly via permlane/DPP.

#define DD 512
#define NN 128
#define NTHREADS 512
#define BB 16
#define NBLK (DD / BB)

__device__ __forceinline__ float lane_bcast(float v, int l) {
  // l is wave-uniform -> v_readlane_b32 (no LDS traffic), bit-exact.
  return __int_as_float(__builtin_amdgcn_readlane(__float_as_int(v), l));
}

__device__ __forceinline__ float wave_reduce_add64(float sd) {
  // == for off in {32,16,8,4,2,1}: sd += xor-partner (pairing preserved).
#if __has_builtin(__builtin_amdgcn_permlane32_swap)
  {
    unsigned xi = __float_as_uint(sd);
    auto r = __builtin_amdgcn_permlane32_swap(xi, xi, false, false);
    sd = __uint_as_float(r[0]) + __uint_as_float(r[1]);
  }
#else
  sd += __shfl_xor(sd, 32, 64);
#endif
#if __has_builtin(__builtin_amdgcn_permlane16_swap)
  {
    unsigned xi = __float_as_uint(sd);
    auto r = __builtin_amdgcn_permlane16_swap(xi, xi, false, false);
    sd = __uint_as_float(r[0]) + __uint_as_float(r[1]);
  }
#else
  sd += __shfl_xor(sd, 16, 64);
#endif
  sd += __int_as_float(
      __builtin_amdgcn_update_dpp(0, __float_as_int(sd), 0x128, 0xF, 0xF, true));
  sd += __int_as_float(
      __builtin_amdgcn_ds_swizzle(__float_as_int(sd), 0x101F));
  sd += __int_as_float(
      __builtin_amdgcn_update_dpp(0, __float_as_int(sd), 0x4E, 0xF, 0xF, true));
  sd += __int_as_float(
      __builtin_amdgcn_update_dpp(0, __float_as_int(sd), 0xB1, 0xF, 0xF, true));
  return sd;
}

__global__ __launch_bounds__(NTHREADS) void slater_scan_kernel(
    const float* __restrict__ P, const float* __restrict__ u,
    float* __restrict__ out) {
  const int tid   = threadIdx.x;
  const int wave  = tid >> 6;
  const int lane  = tid & 63;
  const int c0    = wave << 4;   // first A-column owned by this wave
  const int rbase = c0 & 63;     // readlane base within the row-half
  const bool lowhalf = (wave < 4);

  // part: per-wave partial V, [wave][lane][2rows x 16t], stride 36 (pad,
  //       144B row base keeps float4 alignment + spreads banks).
  __shared__ __align__(16) float part[8][64][36];   // 73728 B
  __shared__ __align__(16) float Vld[128][20];      // 10240 B (compact V)
  __shared__ __align__(16) float Cld[16][20];       //  1280 B (C matrix)

  // Zero cond_probs region (harness poisons d_out).
  for (int j = tid; j < NN * DD; j += NTHREADS) out[j] = 0.0f;

  // u in registers: lane holds entries {lane, lane+64}.
  const float ur0 = u[lane];
  const float ur1 = u[64 + lane];

  // A = I_N distributed into registers.
  float A0[16], A1[16];
#pragma unroll
  for (int j = 0; j < 16; ++j) {
    A0[j] = (lane == c0 + j) ? 1.0f : 0.0f;
    A1[j] = (lane + 64 == c0 + j) ? 1.0f : 0.0f;
  }

  // Decision state, replicated bit-identically in every thread.
  float ratio = 1.0f, cumul = 0.0f;
  int k = 0;

  __syncthreads();

  for (int blk = 0; blk < NBLK; ++blk) {
    const int i0 = blk * BB;

    // ---- P block rows into registers: lane holds p_t[lane], p_t[lane+64]
    float Pb0[16], Pb1[16];
    {
      const float* Pbase = P + i0 * NN + lane;
#pragma unroll
      for (int t = 0; t < 16; ++t) {
        Pb0[t] = Pbase[t * NN];
        Pb1[t] = Pbase[t * NN + 64];
      }
    }

    // ---- phase 1: partial V over this wave's 16 columns (no LDS) ----
    float pa0[16], pa1[16];
#pragma unroll
    for (int t = 0; t < 16; ++t) { pa0[t] = 0.0f; pa1[t] = 0.0f; }
    {
      auto body = [&](const float (&Pbh)[16]) {
#pragma unroll
        for (int j = 0; j < 16; ++j) {
          const float a0 = A0[j], a1 = A1[j];
#pragma unroll
          for (int t = 0; t < 16; ++t) {
            const float pcj = lane_bcast(Pbh[t], rbase + j);  // p_t[c0+j]
            pa0[t] = fmaf(a0, pcj, pa0[t]);
            pa1[t] = fmaf(a1, pcj, pa1[t]);
          }
        }
      };
      if (lowhalf) body(Pb0); else body(Pb1);
    }
    {
      float4* myp = (float4*)&part[wave][lane][0];
      myp[0] = make_float4(pa0[0],  pa0[1],  pa0[2],  pa0[3]);
      myp[1] = make_float4(pa0[4],  pa0[5],  pa0[6],  pa0[7]);
      myp[2] = make_float4(pa0[8],  pa0[9],  pa0[10], pa0[11]);
      myp[3] = make_float4(pa0[12], pa0[13], pa0[14], pa0[15]);
      myp[4] = make_float4(pa1[0],  pa1[1],  pa1[2],  pa1[3]);
      myp[5] = make_float4(pa1[4],  pa1[5],  pa1[6],  pa1[7]);
      myp[6] = make_float4(pa1[8],  pa1[9],  pa1[10], pa1[11]);
      myp[7] = make_float4(pa1[12], pa1[13], pa1[14], pa1[15]);
    }
    __syncthreads();  // barrier 1

    // ---- combine ONCE into compact Vld (each (row,t-quad) summed by one
    //      thread; fixed v-order -> deterministic) ----
    {
      const int r  = tid >> 2;            // output row 0..127
      const int qd = tid & 3;             // t-quad
      const int rl = r & 63;
      const int rh = (r >> 6) << 4;       // 0: rows l, 16: rows l+64
      float s0 = 0.f, s1 = 0.f, s2 = 0.f, s3 = 0.f;
#pragma unroll
      for (int v = 0; v < 8; ++v) {
        const float4 x = *(const float4*)&part[v][rl][rh + 4 * qd];
        s0 += x.x; s1 += x.y; s2 += x.z; s3 += x.w;
      }
      *(float4*)&Vld[r][4 * qd] = make_float4(s0, s1, s2, s3);
    }
    __syncthreads();  // barrier 2

    // ---- V into registers (becomes W in place during the scan) ----
    float W0[16], W1[16];
#pragma unroll
    for (int qd = 0; qd < 4; ++qd) {
      const float4 x = *(const float4*)&Vld[lane][4 * qd];
      W0[4 * qd + 0] = x.x; W0[4 * qd + 1] = x.y;
      W0[4 * qd + 2] = x.z; W0[4 * qd + 3] = x.w;
      const float4 y = *(const float4*)&Vld[lane + 64][4 * qd];
      W1[4 * qd + 0] = y.x; W1[4 * qd + 1] = y.y;
      W1[4 * qd + 2] = y.z; W1[4 * qd + 3] = y.w;
    }

    // ---- C rows {2*wave, 2*wave+1}: C[t][m] = sum_r p_t[r] V[r][m] ----
    {
      float pt0l = 0.f, pt0h = 0.f, pt1l = 0.f, pt1h = 0.f;
#pragma unroll
      for (int j = 0; j < 16; j += 2) {   // static extract of Pb[2w],[2w+1]
        const bool sel = (wave == (j >> 1));
        pt0l = sel ? Pb0[j]     : pt0l;  pt0h = sel ? Pb1[j]     : pt0h;
        pt1l = sel ? Pb0[j + 1] : pt1l;  pt1h = sel ? Pb1[j + 1] : pt1h;
      }
      float cr0[16], cr1[16];
#pragma unroll
      for (int mm = 0; mm < 16; ++mm) {
        cr0[mm] = wave_reduce_add64(fmaf(pt0l, W0[mm], pt0h * W1[mm]));
        cr1[mm] = wave_reduce_add64(fmaf(pt1l, W0[mm], pt1h * W1[mm]));
      }
      if (lane == 0) {
        float4* cp0 = (float4*)&Cld[2 * wave][0];
        cp0[0] = make_float4(cr0[0],  cr0[1],  cr0[2],  cr0[3]);
        cp0[1] = make_float4(cr0[4],  cr0[5],  cr0[6],  cr0[7]);
        cp0[2] = make_float4(cr0[8],  cr0[9],  cr0[10], cr0[11]);
        cp0[3] = make_float4(cr0[12], cr0[13], cr0[14], cr0[15]);
        float4* cp1 = (float4*)&Cld[2 * wave + 1][0];
        cp1[0] = make_float4(cr1[0],  cr1[1],  cr1[2],  cr1[3]);
        cp1[1] = make_float4(cr1[4],  cr1[5],  cr1[6],  cr1[7]);
        cp1[2] = make_float4(cr1[8],  cr1[9],  cr1[10], cr1[11]);
        cp1[3] = make_float4(cr1[12], cr1[13], cr1[14], cr1[15]);
      }
    }
    __syncthreads();  // barrier 3

    // ---- fused decision scan + W-transform (replicated per wave; lane m
    //      owns D column m; all broadcasts from lanes 0..15) ----
    const int m = lane & 15;
    float Cc[16];
#pragma unroll
    for (int t = 0; t < 16; ++t) Cc[t] = Cld[t][m];
    float qdiag = Cld[m][m];   // C[m][m] + running sum of D[j][m]^2/pivot_j
    float Dreg[16];
    float invpv[16];
    bool done = false;
#pragma unroll
    for (int t = 0; t < 16; ++t) {
      const float s = 1.0f - lane_bcast(qdiag, t);   // s_t from lane t
      const int i = i0 + t;
      const int last_allowed = DD - NN + k;
      const bool active = (k < NN) && (i <= last_allowed);
      const float pr = active ? (-(s - 1.0f) * ratio) : 0.0f;
      const int kidx = (k < NN) ? k : (NN - 1);
      const float uk_l = lane_bcast(ur0, kidx & 63);
      const float uk_h = lane_bcast(ur1, kidx & 63);
      const float uk = (kidx < 64) ? uk_l : uk_h;
      const bool occupy = active && ((cumul + pr >= uk) || (i == last_allowed));
      float pivot = occupy ? (s - 1.0f) : s;
      pivot = (fabsf(pivot) < 1e-30f) ? 1e-30f : pivot;
      const float invp = 1.0f / pivot;

      if (tid == 0) {
        if (k < NN) out[k * DD + i] = pr;         // cond_probs[k, i]
        if (occupy) out[NN * DD + k] = (float)i;  // positions[k]
      }

      ratio = occupy ? 1.0f : (active ? ratio * s : ratio);
      cumul = occupy ? 0.0f : (cumul + pr);
      k += occupy ? 1 : 0;
      if (k == NN) { done = true; break; }  // uniform; outputs complete

      // Row t of D and column t of W (w_t = V_t + sum_j f_jt w_j).
      float d = Cc[t];
#pragma unroll
      for (int j = 0; j < t; ++j) {
        const float f = lane_bcast(Dreg[j], t) * invpv[j];  // f_jt
        d     = fmaf(f, Dreg[j], d);
        W0[t] = fmaf(f, W0[j], W0[t]);
        W1[t] = fmaf(f, W1[j], W1[t]);
      }
      Dreg[t]  = d;
      invpv[t] = invp;
      qdiag = fmaf(d * invp, d, qdiag);
    }
    if (done) return;  // uniform across all threads

    // ---- rank-16 update: A[r][c] += sum_t W[r][t]*invp_t*W[c][t] ----
    {
      float Ws0[16], Ws1[16];
#pragma unroll
      for (int t = 0; t < 16; ++t) {
        Ws0[t] = W0[t] * invpv[t];
        Ws1[t] = W1[t] * invpv[t];
      }
      auto upd = [&](const float (&Wh)[16]) {
#pragma unroll
        for (int j = 0; j < 16; ++j) {
#pragma unroll
          for (int t = 0; t < 16; ++t) {
            const float wc = lane_bcast(Wh[t], rbase + j);  // W[c0+j][t]
            A0[j] = fmaf(Ws0[t], wc, A0[j]);
            A1[j] = fmaf(Ws1[t], wc, A1[j]);
          }
        }
      };
      if (lowhalf) upd(W0); else upd(W1);
    }
    // No trailing barrier needed: next block's part/Vld/Cld writes are
    // ordered behind its own barriers 1/2, and this block's LDS reads all
    // completed before barrier 2/3 above.
  }
}

extern "C" void kernel_launch(void* const* d_in, const int* in_sizes, int n_in,
                              void* d_out, int out_size, void* d_ws,
                              size_t ws_size, hipStream_t stream) {
  const float* P = (const float*)d_in[0];  // (512, 128) row-major fp32
  const float* u = (const float*)d_in[1];  // (128,) fp32
  float* out = (float*)d_out;              // 65536 cond_probs + 128 positions
  hipLaunchKernelGGL(slater_scan_kernel, dim3(1), dim3(NTHREADS), 0, stream,
                     P, u, out);
}

// Round 3
// 484.387 us; speedup vs baseline: 1.5277x; 1.0075x over previous
//
#include <hip/hip_runtime.h>

// Slater-determinant ordered sampler, D=512 sites, N=128 particles.
//
// Blocked (B=16) form of the verified N x N recursion:
//   per site: w = A p;  s = 1 - p.w;  <decision>;  A += w w^T / pivot.
// Exact left-looking identity (A symmetric throughout):
//   V = A0 P_B^T                         (heavy, parallel)
//   C = P_B V                            (16x16)
//   scan on C:  D[j][t] = C[j][t] + sum_{l<j} f_lj D[l][t],
//               f_jt = D[j][t]/pivot_j,
//               s_t  = 1 - (C[t][t] + sum_{j<t} D[j][t]^2/pivot_j)
//   w_t = V_t + sum_{j<t} f_jt w_j       (fused into scan)
//   A  += W diag(1/pivot) W^T            (rank-16, parallel)
//
// R3: the kernel is VALU-issue-bound on one CU (R2: 81% per-CU VALUBusy).
// Cut instruction count:
//   - all heavy FMAs -> v_pk_fma_f32 (2 fp32 MACs/instr, the native fp32
//     rate on gfx950); A stored as column-pair v2f registers
//   - phase-1 P broadcasts are wave-uniform -> uniform (readfirstlane-based)
//     addresses so the compiler emits s_load into SGPRs; the SGPR pair
//     feeds VOP3P directly ("s" asm constraint) -> 256 readlanes deleted
//   - rank-16 update: W-column pairs via 2 readlanes -> SGPR pair source
//   - scan keeps running scaled rows SW = W*invp (doubles as the update's
//     scaled operand; the old separate Ws pass deleted)
//
// Layout: wave v (of 8) owns A cols [16v,16v+16); lane l owns rows {l,l+64}.

#define DD 512
#define NN 128
#define NTHREADS 512
#define BB 16
#define NBLK (DD / BB)

typedef float v2f __attribute__((ext_vector_type(2)));

__device__ __forceinline__ float lane_bcast(float v, int l) {
  // l is wave-uniform -> v_readlane_b32, bit-exact.
  return __int_as_float(__builtin_amdgcn_readlane(__float_as_int(v), l));
}

// acc(lo,hi) += a(lo,hi) * bs(lo,hi), bs in SGPR pair (wave-uniform).
__device__ __forceinline__ void pk_fma_vs(v2f& acc, v2f a, v2f bs) {
  asm("v_pk_fma_f32 %0, %1, %2, %0" : "+v"(acc) : "v"(a), "s"(bs));
}
__device__ __forceinline__ v2f pk_mul_vs(v2f a, v2f bs) {
  v2f d;
  asm("v_pk_mul_f32 %0, %1, %2" : "=v"(d) : "v"(a), "s"(bs));
  return d;
}

__device__ __forceinline__ float wave_reduce_add64(float sd) {
  // == for off in {32,16,8,4,2,1}: sd += xor-partner (pairing preserved).
#if __has_builtin(__builtin_amdgcn_permlane32_swap)
  {
    unsigned xi = __float_as_uint(sd);
    auto r = __builtin_amdgcn_permlane32_swap(xi, xi, false, false);
    sd = __uint_as_float(r[0]) + __uint_as_float(r[1]);
  }
#else
  sd += __shfl_xor(sd, 32, 64);
#endif
#if __has_builtin(__builtin_amdgcn_permlane16_swap)
  {
    unsigned xi = __float_as_uint(sd);
    auto r = __builtin_amdgcn_permlane16_swap(xi, xi, false, false);
    sd = __uint_as_float(r[0]) + __uint_as_float(r[1]);
  }
#else
  sd += __shfl_xor(sd, 16, 64);
#endif
  sd += __int_as_float(
      __builtin_amdgcn_update_dpp(0, __float_as_int(sd), 0x128, 0xF, 0xF, true));
  sd += __int_as_float(
      __builtin_amdgcn_ds_swizzle(__float_as_int(sd), 0x101F));
  sd += __int_as_float(
      __builtin_amdgcn_update_dpp(0, __float_as_int(sd), 0x4E, 0xF, 0xF, true));
  sd += __int_as_float(
      __builtin_amdgcn_update_dpp(0, __float_as_int(sd), 0xB1, 0xF, 0xF, true));
  return sd;
}

__global__ __launch_bounds__(NTHREADS) void slater_scan_kernel(
    const float* __restrict__ P, const float* __restrict__ u,
    float* __restrict__ out) {
  const int tid   = threadIdx.x;
  const int wave  = tid >> 6;
  const int lane  = tid & 63;
  const int c0    = wave << 4;   // first A-column owned by this wave
  const int rbase = c0 & 63;     // readlane base within the row-half
  const bool lowhalf = (wave < 4);

  __shared__ __align__(16) float part[8][64][36];   // per-wave partial V
  __shared__ __align__(16) float Vld[128][20];      // combined V
  __shared__ __align__(16) float Cld[16][20];       // C matrix

  // Zero cond_probs region (harness poisons d_out).
  for (int j = tid; j < NN * DD; j += NTHREADS) out[j] = 0.0f;

  // u in registers: lane holds entries {lane, lane+64}.
  const float ur0 = u[lane];
  const float ur1 = u[64 + lane];

  // A = I_N, column-pair packed: A2r0[jp] = (A[lane][c0+2jp], A[lane][c0+2jp+1])
  v2f A2r0[8], A2r1[8];
#pragma unroll
  for (int jp = 0; jp < 8; ++jp) {
    A2r0[jp] = (v2f){(lane == c0 + 2 * jp) ? 1.0f : 0.0f,
                     (lane == c0 + 2 * jp + 1) ? 1.0f : 0.0f};
    A2r1[jp] = (v2f){(lane + 64 == c0 + 2 * jp) ? 1.0f : 0.0f,
                     (lane + 64 == c0 + 2 * jp + 1) ? 1.0f : 0.0f};
  }

  // Decision state, replicated bit-identically in every thread.
  float ratio = 1.0f, cumul = 0.0f;
  int k = 0;

  __syncthreads();

  for (int blk = 0; blk < NBLK; ++blk) {
    const int i0 = blk * BB;
    const int c0u = __builtin_amdgcn_readfirstlane(c0);
    const float* Pu = P + i0 * NN + c0u;   // uniform -> s_load territory

    // p values for this wave's two C rows (divergent loads, issued early).
    const int tr = i0 + 2 * wave;
    const float pt0l = P[tr * NN + lane];
    const float pt0h = P[tr * NN + 64 + lane];
    const float pt1l = P[tr * NN + NN + lane];
    const float pt1h = P[tr * NN + NN + 64 + lane];

    // ---- phase 1: V-partial over this wave's 16 columns ----
    // pa[t] = sum_j A[row][c0+j] * p_t[c0+j]; P entries via SGPR pairs.
    float pa0[16], pa1[16];
#pragma unroll
    for (int t = 0; t < 16; ++t) {
      const v2f* pr2 = (const v2f*)(Pu + t * NN);
      v2f a0 = pk_mul_vs(A2r0[0], pr2[0]);
      v2f a1 = pk_mul_vs(A2r1[0], pr2[0]);
#pragma unroll
      for (int jp = 1; jp < 8; ++jp) {
        const v2f sp = pr2[jp];
        pk_fma_vs(a0, A2r0[jp], sp);
        pk_fma_vs(a1, A2r1[jp], sp);
      }
      pa0[t] = a0.x + a0.y;
      pa1[t] = a1.x + a1.y;
    }
    {
      float4* myp = (float4*)&part[wave][lane][0];
      myp[0] = make_float4(pa0[0],  pa0[1],  pa0[2],  pa0[3]);
      myp[1] = make_float4(pa0[4],  pa0[5],  pa0[6],  pa0[7]);
      myp[2] = make_float4(pa0[8],  pa0[9],  pa0[10], pa0[11]);
      myp[3] = make_float4(pa0[12], pa0[13], pa0[14], pa0[15]);
      myp[4] = make_float4(pa1[0],  pa1[1],  pa1[2],  pa1[3]);
      myp[5] = make_float4(pa1[4],  pa1[5],  pa1[6],  pa1[7]);
      myp[6] = make_float4(pa1[8],  pa1[9],  pa1[10], pa1[11]);
      myp[7] = make_float4(pa1[12], pa1[13], pa1[14], pa1[15]);
    }
    __syncthreads();  // barrier 1

    // ---- combine once into Vld (fixed v-order -> deterministic) ----
    {
      const int r  = tid >> 2;            // output row 0..127
      const int qd = tid & 3;             // t-quad
      const int rl = r & 63;
      const int rh = (r >> 6) << 4;
      float s0 = 0.f, s1 = 0.f, s2 = 0.f, s3 = 0.f;
#pragma unroll
      for (int v = 0; v < 8; ++v) {
        const float4 x = *(const float4*)&part[v][rl][rh + 4 * qd];
        s0 += x.x; s1 += x.y; s2 += x.z; s3 += x.w;
      }
      *(float4*)&Vld[r][4 * qd] = make_float4(s0, s1, s2, s3);
    }
    __syncthreads();  // barrier 2

    // ---- V rows into registers (become W in place during the scan) ----
    float W0[16], W1[16];
#pragma unroll
    for (int qd = 0; qd < 4; ++qd) {
      const float4 x = *(const float4*)&Vld[lane][4 * qd];
      W0[4 * qd + 0] = x.x; W0[4 * qd + 1] = x.y;
      W0[4 * qd + 2] = x.z; W0[4 * qd + 3] = x.w;
      const float4 y = *(const float4*)&Vld[lane + 64][4 * qd];
      W1[4 * qd + 0] = y.x; W1[4 * qd + 1] = y.y;
      W1[4 * qd + 2] = y.z; W1[4 * qd + 3] = y.w;
    }

    // ---- C rows {2w, 2w+1}: C[t][m] = sum_r p_t[r] V[r][m] ----
    {
      float cr0[16], cr1[16];
#pragma unroll
      for (int mm = 0; mm < 16; ++mm) {
        cr0[mm] = wave_reduce_add64(fmaf(pt0l, W0[mm], pt0h * W1[mm]));
        cr1[mm] = wave_reduce_add64(fmaf(pt1l, W0[mm], pt1h * W1[mm]));
      }
      if (lane == 0) {
        float4* cp0 = (float4*)&Cld[2 * wave][0];
        cp0[0] = make_float4(cr0[0],  cr0[1],  cr0[2],  cr0[3]);
        cp0[1] = make_float4(cr0[4],  cr0[5],  cr0[6],  cr0[7]);
        cp0[2] = make_float4(cr0[8],  cr0[9],  cr0[10], cr0[11]);
        cp0[3] = make_float4(cr0[12], cr0[13], cr0[14], cr0[15]);
        float4* cp1 = (float4*)&Cld[2 * wave + 1][0];
        cp1[0] = make_float4(cr1[0],  cr1[1],  cr1[2],  cr1[3]);
        cp1[1] = make_float4(cr1[4],  cr1[5],  cr1[6],  cr1[7]);
        cp1[2] = make_float4(cr1[8],  cr1[9],  cr1[10], cr1[11]);
        cp1[3] = make_float4(cr1[12], cr1[13], cr1[14], cr1[15]);
      }
    }
    __syncthreads();  // barrier 3

    // ---- fused decision scan + W-transform (replicated; lane m owns
    //      D column m). SD/SW = invp-scaled D/W rows, computed once per
    //      row; SW doubles as the scaled operand of the rank-16 update.
    const int m = lane & 15;
    float Cc[16];
#pragma unroll
    for (int t = 0; t < 16; ++t) Cc[t] = Cld[t][m];
    float qdiag = Cld[m][m];
    float Dreg[16], SD[16], SW0[16], SW1[16];
    bool done = false;
#pragma unroll
    for (int t = 0; t < 16; ++t) {
      const float s = 1.0f - lane_bcast(qdiag, t);   // s_t from lane t
      const int i = i0 + t;
      const int last_allowed = DD - NN + k;
      const bool active = (k < NN) && (i <= last_allowed);
      const float pr = active ? (-(s - 1.0f) * ratio) : 0.0f;
      const int kidx = (k < NN) ? k : (NN - 1);
      const float uk_l = lane_bcast(ur0, kidx & 63);
      const float uk_h = lane_bcast(ur1, kidx & 63);
      const float uk = (kidx < 64) ? uk_l : uk_h;
      const bool occupy = active && ((cumul + pr >= uk) || (i == last_allowed));
      float pivot = occupy ? (s - 1.0f) : s;
      pivot = (fabsf(pivot) < 1e-30f) ? 1e-30f : pivot;
      const float invp = 1.0f / pivot;

      if (tid == 0) {
        if (k < NN) out[k * DD + i] = pr;         // cond_probs[k, i]
        if (occupy) out[NN * DD + k] = (float)i;  // positions[k]
      }

      ratio = occupy ? 1.0f : (active ? ratio * s : ratio);
      cumul = occupy ? 0.0f : (cumul + pr);
      k += occupy ? 1 : 0;
      if (k == NN) { done = true; break; }  // uniform; outputs complete

      // Row t of D; w_t = V_t + sum_j f_jt w_j, f_jt = D[j][t]*invp_j.
      float d = Cc[t];
#pragma unroll
      for (int j = 0; j < t; ++j) {
        const float djt = lane_bcast(Dreg[j], t);
        d     = fmaf(djt, SD[j],  d);
        W0[t] = fmaf(djt, SW0[j], W0[t]);
        W1[t] = fmaf(djt, SW1[j], W1[t]);
      }
      Dreg[t] = d;
      SD[t]   = d * invp;
      SW0[t]  = W0[t] * invp;
      SW1[t]  = W1[t] * invp;
      qdiag   = fmaf(d, SD[t], qdiag);
    }
    if (done) return;  // uniform across all threads

    // ---- rank-16 update: A[r][c] += SW[r][t] * W[c][t] ----
    // Column pair (wc_j, wc_j+1) via 2 readlanes -> SGPR pair source.
    {
      auto upd = [&](const float (&Wh)[16]) {
#pragma unroll
        for (int t = 0; t < 16; ++t) {
          const v2f w0d = {SW0[t], SW0[t]};
          const v2f w1d = {SW1[t], SW1[t]};
#pragma unroll
          for (int jp = 0; jp < 8; ++jp) {
            const v2f wc2 = {lane_bcast(Wh[t], rbase + 2 * jp),
                             lane_bcast(Wh[t], rbase + 2 * jp + 1)};
            pk_fma_vs(A2r0[jp], w0d, wc2);
            pk_fma_vs(A2r1[jp], w1d, wc2);
          }
        }
      };
      if (lowhalf) upd(W0); else upd(W1);
    }
    // No trailing barrier needed: next block's LDS writes are behind its
    // own barriers; this block's LDS reads completed before barrier 2/3.
  }
}

extern "C" void kernel_launch(void* const* d_in, const int* in_sizes, int n_in,
                              void* d_out, int out_size, void* d_ws,
                              size_t ws_size, hipStream_t stream) {
  const float* P = (const float*)d_in[0];  // (512, 128) row-major fp32
  const float* u = (const float*)d_in[1];  // (128,) fp32
  float* out = (float*)d_out;              // 65536 cond_probs + 128 positions
  hipLaunchKernelGGL(slater_scan_kernel, dim3(1), dim3(NTHREADS), 0, stream,
                     P, u, out);
}

// Round 4
// 464.249 us; speedup vs baseline: 1.5939x; 1.0434x over previous
//
#include <hip/hip_runtime.h>

// Slater-determinant ordered sampler, D=512 sites, N=128 particles.
//
// Blocked (B=16) form of the verified N x N recursion:
//   per site: w = A p;  s = 1 - p.w;  <decision>;  A += w w^T / pivot.
// Exact left-looking identity (A symmetric throughout):
//   V = A0 P_B^T;  C = P_B V;  scan on C (D/qdiag recurrence) fused with
//   w_t = V_t + sum_{j<t} f_jt w_j;  A += W diag(1/pivot) W^T.
//
// R4 (post R3's neutral result: VALU issue fell 25% but s_load lgkm stalls
// ate it):
//   - phase-1 P broadcasts via wave-uniform LDS b128 reads from a
//     double-buffered staged P block (same-address = HW broadcast, deep
//     pipelining; replaces 256 readlanes / stalling s_loads per block)
//   - V transposed in LDS: VldT[16][129] -> conflict-free b32 W-loads
//     (fixes the measured SQ_LDS_BANK_CONFLICT=10240 from Vld[128][20])
//     and Wp pairs {V[l][m],V[l+64][m]} load straight into register pairs
//   - scan W-transform packed: v2f Wp/SWp, multiplier dup on the scalar
//     pipe (readlane->SGPR + s_mov), 1 pk_fma instead of 2 fma
//   - update keeps R3's readlane-pair + pk form (proven, no new stalls)
// All FP op orders bit-identical to R3 (pk even/odd split, per-component
// chains, reduction pairing all unchanged; layout changes only).
//
// Layout: wave v (of 8) owns A cols [16v,16v+16); lane l owns rows {l,l+64}.

#define DD 512
#define NN 128
#define NTHREADS 512
#define BB 16
#define NBLK (DD / BB)

typedef float v2f __attribute__((ext_vector_type(2)));

__device__ __forceinline__ float lane_bcast(float v, int l) {
  // l wave-uniform -> v_readlane_b32 (SGPR dest), bit-exact.
  return __int_as_float(__builtin_amdgcn_readlane(__float_as_int(v), l));
}
__device__ __forceinline__ void pk_fma_vv(v2f& acc, v2f a, v2f b) {
  asm("v_pk_fma_f32 %0, %1, %2, %0" : "+v"(acc) : "v"(a), "v"(b));
}
__device__ __forceinline__ void pk_fma_vs(v2f& acc, v2f a, v2f bs) {
  asm("v_pk_fma_f32 %0, %1, %2, %0" : "+v"(acc) : "v"(a), "s"(bs));
}
__device__ __forceinline__ v2f pk_mul_vv(v2f a, v2f b) {
  v2f d;
  asm("v_pk_mul_f32 %0, %1, %2" : "=v"(d) : "v"(a), "v"(b));
  return d;
}
__device__ __forceinline__ void pk_add_vv(v2f& acc, v2f a) {
  asm("v_pk_add_f32 %0, %1, %0" : "+v"(acc) : "v"(a));
}

__device__ __forceinline__ float wave_reduce_add64(float sd) {
  // == for off in {32,16,8,4,2,1}: sd += xor-partner (pairing preserved).
#if __has_builtin(__builtin_amdgcn_permlane32_swap)
  {
    unsigned xi = __float_as_uint(sd);
    auto r = __builtin_amdgcn_permlane32_swap(xi, xi, false, false);
    sd = __uint_as_float(r[0]) + __uint_as_float(r[1]);
  }
#else
  sd += __shfl_xor(sd, 32, 64);
#endif
#if __has_builtin(__builtin_amdgcn_permlane16_swap)
  {
    unsigned xi = __float_as_uint(sd);
    auto r = __builtin_amdgcn_permlane16_swap(xi, xi, false, false);
    sd = __uint_as_float(r[0]) + __uint_as_float(r[1]);
  }
#else
  sd += __shfl_xor(sd, 16, 64);
#endif
  sd += __int_as_float(
      __builtin_amdgcn_update_dpp(0, __float_as_int(sd), 0x128, 0xF, 0xF, true));
  sd += __int_as_float(
      __builtin_amdgcn_ds_swizzle(__float_as_int(sd), 0x101F));
  sd += __int_as_float(
      __builtin_amdgcn_update_dpp(0, __float_as_int(sd), 0x4E, 0xF, 0xF, true));
  sd += __int_as_float(
      __builtin_amdgcn_update_dpp(0, __float_as_int(sd), 0xB1, 0xF, 0xF, true));
  return sd;
}

__global__ __launch_bounds__(NTHREADS) void slater_scan_kernel(
    const float* __restrict__ P, const float* __restrict__ u,
    float* __restrict__ out) {
  const int tid   = threadIdx.x;
  const int wave  = tid >> 6;
  const int lane  = tid & 63;
  const int c0    = wave << 4;   // first A-column owned by this wave
  const int rbase = c0 & 63;     // readlane base within the row-half
  const bool lowhalf = (wave < 4);

  __shared__ __align__(16) float part[8][64][36];   // per-wave partial V
  __shared__ __align__(16) float VldT[16][129];     // V transposed (+pad)
  __shared__ __align__(16) float Cld[16][20];       // C matrix
  __shared__ __align__(16) float Pst[2][BB][NN];    // staged P blocks (dbuf)

  // Zero cond_probs region (harness poisons d_out).
  for (int j = tid; j < NN * DD; j += NTHREADS) out[j] = 0.0f;

  // u in registers: lane holds entries {lane, lane+64}.
  const float ur0 = u[lane];
  const float ur1 = u[64 + lane];

  // Stage P block 0: thread -> one float4 (coalesced).
  const int sr = tid >> 5;          // staged row 0..15
  const int sc = (tid & 31) << 2;   // staged col (x4)
  *(float4*)&Pst[0][sr][sc] = *(const float4*)&P[sr * NN + sc];

  // A = I_N, column-pair packed.
  v2f A2r0[8], A2r1[8];
#pragma unroll
  for (int jp = 0; jp < 8; ++jp) {
    A2r0[jp] = (v2f){(lane == c0 + 2 * jp) ? 1.0f : 0.0f,
                     (lane == c0 + 2 * jp + 1) ? 1.0f : 0.0f};
    A2r1[jp] = (v2f){(lane + 64 == c0 + 2 * jp) ? 1.0f : 0.0f,
                     (lane + 64 == c0 + 2 * jp + 1) ? 1.0f : 0.0f};
  }

  // Decision state, replicated bit-identically in every thread.
  float ratio = 1.0f, cumul = 0.0f;
  int k = 0;

  __syncthreads();

  for (int blk = 0; blk < NBLK; ++blk) {
    const int i0  = blk * BB;
    const int buf = blk & 1;

    // Early-issue the next block's staging load (consumed pre-bar1).
    float4 stg;
    const bool do_stage = (blk + 1 < NBLK);
    if (do_stage) stg = *(const float4*)&P[(i0 + BB + sr) * NN + sc];

    // This wave's two C-row p values, from the staged block (per-lane b32,
    // stride-1 across lanes -> conflict-free).
    const int t2 = 2 * wave;
    const float pt0l = Pst[buf][t2][lane];
    const float pt0h = Pst[buf][t2][64 + lane];
    const float pt1l = Pst[buf][t2 + 1][lane];
    const float pt1h = Pst[buf][t2 + 1][64 + lane];

    // ---- phase 1: V-partials over this wave's 16 columns; P pairs via
    //      wave-uniform b128 LDS reads (HW broadcast, no readlane/s_load).
    float pa0[16], pa1[16];
#pragma unroll
    for (int t = 0; t < 16; ++t) {
      const float4 q0 = *(const float4*)&Pst[buf][t][c0];
      const float4 q1 = *(const float4*)&Pst[buf][t][c0 + 4];
      const float4 q2 = *(const float4*)&Pst[buf][t][c0 + 8];
      const float4 q3 = *(const float4*)&Pst[buf][t][c0 + 12];
      const v2f pp0 = {q0.x, q0.y}, pp1 = {q0.z, q0.w};
      const v2f pp2 = {q1.x, q1.y}, pp3 = {q1.z, q1.w};
      const v2f pp4 = {q2.x, q2.y}, pp5 = {q2.z, q2.w};
      const v2f pp6 = {q3.x, q3.y}, pp7 = {q3.z, q3.w};
      v2f a0 = pk_mul_vv(A2r0[0], pp0);
      v2f a1 = pk_mul_vv(A2r1[0], pp0);
      pk_fma_vv(a0, A2r0[1], pp1); pk_fma_vv(a1, A2r1[1], pp1);
      pk_fma_vv(a0, A2r0[2], pp2); pk_fma_vv(a1, A2r1[2], pp2);
      pk_fma_vv(a0, A2r0[3], pp3); pk_fma_vv(a1, A2r1[3], pp3);
      pk_fma_vv(a0, A2r0[4], pp4); pk_fma_vv(a1, A2r1[4], pp4);
      pk_fma_vv(a0, A2r0[5], pp5); pk_fma_vv(a1, A2r1[5], pp5);
      pk_fma_vv(a0, A2r0[6], pp6); pk_fma_vv(a1, A2r1[6], pp6);
      pk_fma_vv(a0, A2r0[7], pp7); pk_fma_vv(a1, A2r1[7], pp7);
      pa0[t] = a0.x + a0.y;
      pa1[t] = a1.x + a1.y;
    }
    {
      float4* myp = (float4*)&part[wave][lane][0];
      myp[0] = make_float4(pa0[0],  pa0[1],  pa0[2],  pa0[3]);
      myp[1] = make_float4(pa0[4],  pa0[5],  pa0[6],  pa0[7]);
      myp[2] = make_float4(pa0[8],  pa0[9],  pa0[10], pa0[11]);
      myp[3] = make_float4(pa0[12], pa0[13], pa0[14], pa0[15]);
      myp[4] = make_float4(pa1[0],  pa1[1],  pa1[2],  pa1[3]);
      myp[5] = make_float4(pa1[4],  pa1[5],  pa1[6],  pa1[7]);
      myp[6] = make_float4(pa1[8],  pa1[9],  pa1[10], pa1[11]);
      myp[7] = make_float4(pa1[12], pa1[13], pa1[14], pa1[15]);
    }
    if (do_stage) *(float4*)&Pst[buf ^ 1][sr][sc] = stg;
    __syncthreads();  // barrier 1

    // ---- combine once into VldT (fixed v-order -> deterministic) ----
    {
      const int r  = tid >> 2;            // output row 0..127
      const int qd = tid & 3;             // t-quad
      const int rl = r & 63;
      const int rh = (r >> 6) << 4;
      v2f s01 = {0.0f, 0.0f}, s23 = {0.0f, 0.0f};
#pragma unroll
      for (int v = 0; v < 8; ++v) {
        const float4 x = *(const float4*)&part[v][rl][rh + 4 * qd];
        pk_add_vv(s01, (v2f){x.x, x.y});
        pk_add_vv(s23, (v2f){x.z, x.w});
      }
      VldT[4 * qd + 0][r] = s01.x;
      VldT[4 * qd + 1][r] = s01.y;
      VldT[4 * qd + 2][r] = s23.x;
      VldT[4 * qd + 3][r] = s23.y;
    }
    __syncthreads();  // barrier 2

    // ---- V rows into register pairs (become W during the scan) ----
    v2f Wp[16];
#pragma unroll
    for (int m2 = 0; m2 < 16; ++m2)
      Wp[m2] = (v2f){VldT[m2][lane], VldT[m2][lane + 64]};

    // ---- C rows {2w, 2w+1}: C[t][m] = sum_r p_t[r] V[r][m] ----
    {
      float cr0[16], cr1[16];
#pragma unroll
      for (int mm = 0; mm < 16; ++mm) {
        cr0[mm] = wave_reduce_add64(fmaf(pt0l, Wp[mm].x, pt0h * Wp[mm].y));
        cr1[mm] = wave_reduce_add64(fmaf(pt1l, Wp[mm].x, pt1h * Wp[mm].y));
      }
      if (lane == 0) {
        float4* cp0 = (float4*)&Cld[t2][0];
        cp0[0] = make_float4(cr0[0],  cr0[1],  cr0[2],  cr0[3]);
        cp0[1] = make_float4(cr0[4],  cr0[5],  cr0[6],  cr0[7]);
        cp0[2] = make_float4(cr0[8],  cr0[9],  cr0[10], cr0[11]);
        cp0[3] = make_float4(cr0[12], cr0[13], cr0[14], cr0[15]);
        float4* cp1 = (float4*)&Cld[t2 + 1][0];
        cp1[0] = make_float4(cr1[0],  cr1[1],  cr1[2],  cr1[3]);
        cp1[1] = make_float4(cr1[4],  cr1[5],  cr1[6],  cr1[7]);
        cp1[2] = make_float4(cr1[8],  cr1[9],  cr1[10], cr1[11]);
        cp1[3] = make_float4(cr1[12], cr1[13], cr1[14], cr1[15]);
      }
    }
    __syncthreads();  // barrier 3

    // ---- fused decision scan + W-transform (replicated; lane m owns
    //      D column m; SWp = invp-scaled W rows, reused by the update) ----
    const int m = lane & 15;
    float Cc[16];
#pragma unroll
    for (int t = 0; t < 16; ++t) Cc[t] = Cld[t][m];
    float qdiag = Cld[m][m];
    float Dreg[16], SD[16];
    v2f SWp[16];
    bool done = false;
#pragma unroll
    for (int t = 0; t < 16; ++t) {
      const float s = 1.0f - lane_bcast(qdiag, t);   // s_t from lane t
      const int i = i0 + t;
      const int last_allowed = DD - NN + k;
      const bool active = (k < NN) && (i <= last_allowed);
      const float pr = active ? (-(s - 1.0f) * ratio) : 0.0f;
      const int kidx = (k < NN) ? k : (NN - 1);
      const float uk_l = lane_bcast(ur0, kidx & 63);
      const float uk_h = lane_bcast(ur1, kidx & 63);
      const float uk = (kidx < 64) ? uk_l : uk_h;
      const bool occupy = active && ((cumul + pr >= uk) || (i == last_allowed));
      float pivot = occupy ? (s - 1.0f) : s;
      pivot = (fabsf(pivot) < 1e-30f) ? 1e-30f : pivot;
      const float invp = 1.0f / pivot;

      if (tid == 0) {
        if (k < NN) out[k * DD + i] = pr;         // cond_probs[k, i]
        if (occupy) out[NN * DD + k] = (float)i;  // positions[k]
      }

      ratio = occupy ? 1.0f : (active ? ratio * s : ratio);
      cumul = occupy ? 0.0f : (cumul + pr);
      k += occupy ? 1 : 0;
      if (k == NN) { done = true; break; }  // uniform; outputs complete

      // Row t of D; w_t = V_t + sum_j f_jt w_j, f_jt = D[j][t]*invp_j.
      float d = Cc[t];
#pragma unroll
      for (int j = 0; j < t; ++j) {
        const float djt = lane_bcast(Dreg[j], t);
        d = fmaf(djt, SD[j], d);
        pk_fma_vs(Wp[t], SWp[j], (v2f){djt, djt});  // W += SW * djt
      }
      Dreg[t] = d;
      SD[t]   = d * invp;
      SWp[t]  = pk_mul_vv(Wp[t], (v2f){invp, invp});
      qdiag   = fmaf(d, SD[t], qdiag);
    }
    if (done) return;  // uniform across all threads

    // ---- rank-16 update: A[r][c] += SW[r][t] * W[c][t] ----
    // Column pair via 2 readlanes -> SGPR pair source (R3-proven form).
    {
      auto upd = [&](bool low) {
#pragma unroll
        for (int t = 0; t < 16; ++t) {
          const v2f w0d = {SWp[t].x, SWp[t].x};
          const v2f w1d = {SWp[t].y, SWp[t].y};
          const float wsrc = low ? Wp[t].x : Wp[t].y;
#pragma unroll
          for (int jp = 0; jp < 8; ++jp) {
            const v2f wc2 = {lane_bcast(wsrc, rbase + 2 * jp),
                             lane_bcast(wsrc, rbase + 2 * jp + 1)};
            pk_fma_vs(A2r0[jp], w0d, wc2);
            pk_fma_vs(A2r1[jp], w1d, wc2);
          }
        }
      };
      if (lowhalf) upd(true); else upd(false);
    }
    // No trailing barrier: next block's LDS writes sit behind its own
    // barriers; this block's LDS reads completed before bar2/bar3.
  }
}

extern "C" void kernel_launch(void* const* d_in, const int* in_sizes, int n_in,
                              void* d_out, int out_size, void* d_ws,
                              size_t ws_size, hipStream_t stream) {
  const float* P = (const float*)d_in[0];  // (512, 128) row-major fp32
  const float* u = (const float*)d_in[1];  // (128,) fp32
  float* out = (float*)d_out;              // 65536 cond_probs + 128 positions
  hipLaunchKernelGGL(slater_scan_kernel, dim3(1), dim3(NTHREADS), 0, stream,
                     P, u, out);
}

// Round 5
// 425.703 us; speedup vs baseline: 1.7383x; 1.0905x over previous
//
#include <hip/hip_runtime.h>

// Slater-determinant ordered sampler, D=512 sites, N=128 particles.
//
// Blocked (B=16) form of the verified N x N recursion:
//   per site: w = A p;  s = 1 - p.w;  <decision>;  A += w w^T / pivot.
// Exact left-looking identity (A symmetric throughout):
//   V = A0 P_B^T;  C = P_B V;  triangular scan on C fused with
//   w_t = V_t + sum_{j<t} f_jt w_j;  A += W diag(1/pivot) W^T.
//
// R5 (post R4: latency-chain-bound, not issue-bound; per-SIMD issue ~7k of
// ~16-31k cyc/block):
//   - RIGHT-LOOKING scan: after pivot t, trailing updates
//       E[t2][m] += bcast(E[t][.],t2) * (E[t][m]*invp_t)
//       W[t2]    += SW[t] * bcast(E[t][.],t2)
//     Issues the IDENTICAL fma ops with IDENTICAL operands in the same
//     j-order as the old left-looking d-chain (term-by-term verified for
//     E, W, and the diagonal/s path) -- but per-step dependency depth is
//     ~(readlane + 1 fma) instead of a t-deep serial chain. Serial scan
//     time ~1700 -> ~600 cyc/block.
//   - update broadcasts via wave-local LDS stash (Wst[wave][16][20]):
//     16 owner-lanes write their W column values (conflict-free b32,
//     no barrier -- wave reads only its own slab), update then reads
//     wave-uniform b128 like phase-1. Kills 256 readlanes/thread.
//   - C-reduce packed: (cr0,cr1) row-pair reduced as v2f (pk_add stages);
//     per-component values and pairing bit-identical.
//
// Layout: wave v (of 8) owns A cols [16v,16v+16); lane l owns rows {l,l+64}.

#define DD 512
#define NN 128
#define NTHREADS 512
#define BB 16
#define NBLK (DD / BB)

typedef float v2f __attribute__((ext_vector_type(2)));

__device__ __forceinline__ float lane_bcast(float v, int l) {
  // l wave-uniform -> v_readlane_b32 (SGPR dest), bit-exact.
  return __int_as_float(__builtin_amdgcn_readlane(__float_as_int(v), l));
}
__device__ __forceinline__ void pk_fma_vv(v2f& acc, v2f a, v2f b) {
  asm("v_pk_fma_f32 %0, %1, %2, %0" : "+v"(acc) : "v"(a), "v"(b));
}
__device__ __forceinline__ void pk_fma_vs(v2f& acc, v2f a, v2f bs) {
  asm("v_pk_fma_f32 %0, %1, %2, %0" : "+v"(acc) : "v"(a), "s"(bs));
}
__device__ __forceinline__ v2f pk_mul_vv(v2f a, v2f b) {
  v2f d;
  asm("v_pk_mul_f32 %0, %1, %2" : "=v"(d) : "v"(a), "v"(b));
  return d;
}
__device__ __forceinline__ void pk_add_vv(v2f& acc, v2f a) {
  asm("v_pk_add_f32 %0, %1, %0" : "+v"(acc) : "v"(a));
}

__device__ __forceinline__ float wave_reduce_add64(float sd) {
  // == for off in {32,16,8,4,2,1}: sd += xor-partner (pairing preserved).
#if __has_builtin(__builtin_amdgcn_permlane32_swap)
  {
    unsigned xi = __float_as_uint(sd);
    auto r = __builtin_amdgcn_permlane32_swap(xi, xi, false, false);
    sd = __uint_as_float(r[0]) + __uint_as_float(r[1]);
  }
#else
  sd += __shfl_xor(sd, 32, 64);
#endif
#if __has_builtin(__builtin_amdgcn_permlane16_swap)
  {
    unsigned xi = __float_as_uint(sd);
    auto r = __builtin_amdgcn_permlane16_swap(xi, xi, false, false);
    sd = __uint_as_float(r[0]) + __uint_as_float(r[1]);
  }
#else
  sd += __shfl_xor(sd, 16, 64);
#endif
  sd += __int_as_float(
      __builtin_amdgcn_update_dpp(0, __float_as_int(sd), 0x128, 0xF, 0xF, true));
  sd += __int_as_float(
      __builtin_amdgcn_ds_swizzle(__float_as_int(sd), 0x101F));
  sd += __int_as_float(
      __builtin_amdgcn_update_dpp(0, __float_as_int(sd), 0x4E, 0xF, 0xF, true));
  sd += __int_as_float(
      __builtin_amdgcn_update_dpp(0, __float_as_int(sd), 0xB1, 0xF, 0xF, true));
  return sd;
}

// Packed pair reduce: component-wise identical to wave_reduce_add64 on each
// half (same stage order, same xor partners); only instruction packing
// differs (pk_add where both halves share a stage).
__device__ __forceinline__ v2f wave_reduce_add64_pk(v2f sd) {
#if __has_builtin(__builtin_amdgcn_permlane32_swap)
  {
    unsigned xl = __float_as_uint(sd.x), xh = __float_as_uint(sd.y);
    auto rl = __builtin_amdgcn_permlane32_swap(xl, xl, false, false);
    auto rh = __builtin_amdgcn_permlane32_swap(xh, xh, false, false);
    v2f partner = {__uint_as_float(rl[1]), __uint_as_float(rh[1])};
    v2f self    = {__uint_as_float(rl[0]), __uint_as_float(rh[0])};
    sd = self;
    pk_add_vv(sd, partner);
  }
#else
  sd.x += __shfl_xor(sd.x, 32, 64);
  sd.y += __shfl_xor(sd.y, 32, 64);
#endif
#if __has_builtin(__builtin_amdgcn_permlane16_swap)
  {
    unsigned xl = __float_as_uint(sd.x), xh = __float_as_uint(sd.y);
    auto rl = __builtin_amdgcn_permlane16_swap(xl, xl, false, false);
    auto rh = __builtin_amdgcn_permlane16_swap(xh, xh, false, false);
    v2f partner = {__uint_as_float(rl[1]), __uint_as_float(rh[1])};
    v2f self    = {__uint_as_float(rl[0]), __uint_as_float(rh[0])};
    sd = self;
    pk_add_vv(sd, partner);
  }
#else
  sd.x += __shfl_xor(sd.x, 16, 64);
  sd.y += __shfl_xor(sd.y, 16, 64);
#endif
  // ^8 per component (DPP-fused adds)
  sd.x += __int_as_float(__builtin_amdgcn_update_dpp(
      0, __float_as_int(sd.x), 0x128, 0xF, 0xF, true));
  sd.y += __int_as_float(__builtin_amdgcn_update_dpp(
      0, __float_as_int(sd.y), 0x128, 0xF, 0xF, true));
  // ^4 via swizzle pair + pk_add
  {
    v2f partner = {
        __int_as_float(__builtin_amdgcn_ds_swizzle(__float_as_int(sd.x), 0x101F)),
        __int_as_float(__builtin_amdgcn_ds_swizzle(__float_as_int(sd.y), 0x101F))};
    pk_add_vv(sd, partner);
  }
  // ^2, ^1 per component
  sd.x += __int_as_float(__builtin_amdgcn_update_dpp(
      0, __float_as_int(sd.x), 0x4E, 0xF, 0xF, true));
  sd.y += __int_as_float(__builtin_amdgcn_update_dpp(
      0, __float_as_int(sd.y), 0x4E, 0xF, 0xF, true));
  sd.x += __int_as_float(__builtin_amdgcn_update_dpp(
      0, __float_as_int(sd.x), 0xB1, 0xF, 0xF, true));
  sd.y += __int_as_float(__builtin_amdgcn_update_dpp(
      0, __float_as_int(sd.y), 0xB1, 0xF, 0xF, true));
  return sd;
}

__global__ __launch_bounds__(NTHREADS) void slater_scan_kernel(
    const float* __restrict__ P, const float* __restrict__ u,
    float* __restrict__ out) {
  const int tid   = threadIdx.x;
  const int wave  = tid >> 6;
  const int lane  = tid & 63;
  const int c0    = wave << 4;   // first A-column owned by this wave
  const bool lowhalf = (wave < 4);

  __shared__ __align__(16) float part[8][64][36];   // per-wave partial V
  __shared__ __align__(16) float VldT[16][129];     // V transposed (+pad)
  __shared__ __align__(16) float Cld[16][20];       // C matrix
  __shared__ __align__(16) float Pst[2][BB][NN];    // staged P blocks (dbuf)
  __shared__ __align__(16) float Wst[8][16][20];    // per-wave W-col stash

  // Zero cond_probs region (harness poisons d_out).
  for (int j = tid; j < NN * DD; j += NTHREADS) out[j] = 0.0f;

  // u in registers: lane holds entries {lane, lane+64}.
  const float ur0 = u[lane];
  const float ur1 = u[64 + lane];

  // Stage P block 0: thread -> one float4 (coalesced).
  const int sr = tid >> 5;          // staged row 0..15
  const int sc = (tid & 31) << 2;   // staged col (x4)
  *(float4*)&Pst[0][sr][sc] = *(const float4*)&P[sr * NN + sc];

  // A = I_N, column-pair packed.
  v2f A2r0[8], A2r1[8];
#pragma unroll
  for (int jp = 0; jp < 8; ++jp) {
    A2r0[jp] = (v2f){(lane == c0 + 2 * jp) ? 1.0f : 0.0f,
                     (lane == c0 + 2 * jp + 1) ? 1.0f : 0.0f};
    A2r1[jp] = (v2f){(lane + 64 == c0 + 2 * jp) ? 1.0f : 0.0f,
                     (lane + 64 == c0 + 2 * jp + 1) ? 1.0f : 0.0f};
  }

  // Decision state, replicated bit-identically in every thread.
  float ratio = 1.0f, cumul = 0.0f;
  int k = 0;

  __syncthreads();

  for (int blk = 0; blk < NBLK; ++blk) {
    const int i0  = blk * BB;
    const int buf = blk & 1;

    // Early-issue the next block's staging load (consumed pre-bar1).
    float4 stg;
    const bool do_stage = (blk + 1 < NBLK);
    if (do_stage) stg = *(const float4*)&P[(i0 + BB + sr) * NN + sc];

    // This wave's two C-row p values from the staged block.
    const int t2r = 2 * wave;
    const float pt0l = Pst[buf][t2r][lane];
    const float pt0h = Pst[buf][t2r][64 + lane];
    const float pt1l = Pst[buf][t2r + 1][lane];
    const float pt1h = Pst[buf][t2r + 1][64 + lane];

    // ---- phase 1: V-partials over this wave's 16 columns; P pairs via
    //      wave-uniform b128 LDS reads (HW broadcast).
    float pa0[16], pa1[16];
#pragma unroll
    for (int t = 0; t < 16; ++t) {
      const float4 q0 = *(const float4*)&Pst[buf][t][c0];
      const float4 q1 = *(const float4*)&Pst[buf][t][c0 + 4];
      const float4 q2 = *(const float4*)&Pst[buf][t][c0 + 8];
      const float4 q3 = *(const float4*)&Pst[buf][t][c0 + 12];
      const v2f pp0 = {q0.x, q0.y}, pp1 = {q0.z, q0.w};
      const v2f pp2 = {q1.x, q1.y}, pp3 = {q1.z, q1.w};
      const v2f pp4 = {q2.x, q2.y}, pp5 = {q2.z, q2.w};
      const v2f pp6 = {q3.x, q3.y}, pp7 = {q3.z, q3.w};
      v2f a0 = pk_mul_vv(A2r0[0], pp0);
      v2f a1 = pk_mul_vv(A2r1[0], pp0);
      pk_fma_vv(a0, A2r0[1], pp1); pk_fma_vv(a1, A2r1[1], pp1);
      pk_fma_vv(a0, A2r0[2], pp2); pk_fma_vv(a1, A2r1[2], pp2);
      pk_fma_vv(a0, A2r0[3], pp3); pk_fma_vv(a1, A2r1[3], pp3);
      pk_fma_vv(a0, A2r0[4], pp4); pk_fma_vv(a1, A2r1[4], pp4);
      pk_fma_vv(a0, A2r0[5], pp5); pk_fma_vv(a1, A2r1[5], pp5);
      pk_fma_vv(a0, A2r0[6], pp6); pk_fma_vv(a1, A2r1[6], pp6);
      pk_fma_vv(a0, A2r0[7], pp7); pk_fma_vv(a1, A2r1[7], pp7);
      pa0[t] = a0.x + a0.y;
      pa1[t] = a1.x + a1.y;
    }
    {
      float4* myp = (float4*)&part[wave][lane][0];
      myp[0] = make_float4(pa0[0],  pa0[1],  pa0[2],  pa0[3]);
      myp[1] = make_float4(pa0[4],  pa0[5],  pa0[6],  pa0[7]);
      myp[2] = make_float4(pa0[8],  pa0[9],  pa0[10], pa0[11]);
      myp[3] = make_float4(pa0[12], pa0[13], pa0[14], pa0[15]);
      myp[4] = make_float4(pa1[0],  pa1[1],  pa1[2],  pa1[3]);
      myp[5] = make_float4(pa1[4],  pa1[5],  pa1[6],  pa1[7]);
      myp[6] = make_float4(pa1[8],  pa1[9],  pa1[10], pa1[11]);
      myp[7] = make_float4(pa1[12], pa1[13], pa1[14], pa1[15]);
    }
    if (do_stage) *(float4*)&Pst[buf ^ 1][sr][sc] = stg;
    __syncthreads();  // barrier 1

    // ---- combine once into VldT (fixed v-order -> deterministic) ----
    {
      const int r  = tid >> 2;            // output row 0..127
      const int qd = tid & 3;             // t-quad
      const int rl = r & 63;
      const int rh = (r >> 6) << 4;
      v2f s01 = {0.0f, 0.0f}, s23 = {0.0f, 0.0f};
#pragma unroll
      for (int v = 0; v < 8; ++v) {
        const float4 x = *(const float4*)&part[v][rl][rh + 4 * qd];
        pk_add_vv(s01, (v2f){x.x, x.y});
        pk_add_vv(s23, (v2f){x.z, x.w});
      }
      VldT[4 * qd + 0][r] = s01.x;
      VldT[4 * qd + 1][r] = s01.y;
      VldT[4 * qd + 2][r] = s23.x;
      VldT[4 * qd + 3][r] = s23.y;
    }
    __syncthreads();  // barrier 2

    // ---- V rows into register pairs (become W during the scan) ----
    v2f Wp[16];
#pragma unroll
    for (int m2 = 0; m2 < 16; ++m2)
      Wp[m2] = (v2f){VldT[m2][lane], VldT[m2][lane + 64]};

    // ---- C rows {2w, 2w+1}: C[t][m] = sum_r p_t[r] V[r][m] ----
    // Pair (cr0,cr1) packed; per-component ops identical to the scalar form.
    {
      v2f cr[16];
#pragma unroll
      for (int mm = 0; mm < 16; ++mm) {
        const v2f wx = {Wp[mm].x, Wp[mm].x};
        const v2f wy = {Wp[mm].y, Wp[mm].y};
        v2f seed = pk_mul_vv((v2f){pt0h, pt1h}, wy);  // {pt0h*Wy, pt1h*Wy}
        pk_fma_vv(seed, (v2f){pt0l, pt1l}, wx);       // fma(ptl, Wx, .)
        cr[mm] = wave_reduce_add64_pk(seed);
      }
      if (lane == 0) {
#pragma unroll
        for (int mm = 0; mm < 16; ++mm) {
          Cld[t2r][mm]     = cr[mm].x;
          Cld[t2r + 1][mm] = cr[mm].y;
        }
      }
    }
    __syncthreads();  // barrier 3

    // ---- fused decision scan + W-transform, RIGHT-LOOKING ----
    // Lane m owns column m of E (= D rows as they finalize).
    const int m = lane & 15;
    float Ereg[16];
#pragma unroll
    for (int t = 0; t < 16; ++t) Ereg[t] = Cld[t][m];
    v2f SWp[16];
    bool done = false;
#pragma unroll
    for (int t = 0; t < 16; ++t) {
      const float s = 1.0f - lane_bcast(Ereg[t], t);   // E[t][t] from lane t
      const int i = i0 + t;
      const int last_allowed = DD - NN + k;
      const bool active = (k < NN) && (i <= last_allowed);
      const float pr = active ? (-(s - 1.0f) * ratio) : 0.0f;
      const int kidx = (k < NN) ? k : (NN - 1);
      const float uk_l = lane_bcast(ur0, kidx & 63);
      const float uk_h = lane_bcast(ur1, kidx & 63);
      const float uk = (kidx < 64) ? uk_l : uk_h;
      const bool occupy = active && ((cumul + pr >= uk) || (i == last_allowed));
      float pivot = occupy ? (s - 1.0f) : s;
      pivot = (fabsf(pivot) < 1e-30f) ? 1e-30f : pivot;
      const float invp = 1.0f / pivot;

      if (tid == 0) {
        if (k < NN) out[k * DD + i] = pr;         // cond_probs[k, i]
        if (occupy) out[NN * DD + k] = (float)i;  // positions[k]
      }

      ratio = occupy ? 1.0f : (active ? ratio * s : ratio);
      cumul = occupy ? 0.0f : (cumul + pr);
      k += occupy ? 1 : 0;
      if (k == NN) { done = true; break; }  // uniform; outputs complete

      // Pivot t's trailing updates. SDl = D[t][m]*invp_t (lane-local);
      // identical operands/order as the old left-looking chain, term by term.
      const float SDl = Ereg[t] * invp;
      SWp[t] = pk_mul_vv(Wp[t], (v2f){invp, invp});
#pragma unroll
      for (int t2 = t + 1; t2 < 16; ++t2) {
        const float djt2 = lane_bcast(Ereg[t], t2);   // D[t][t2]
        Ereg[t2] = fmaf(djt2, SDl, Ereg[t2]);
        pk_fma_vs(Wp[t2], SWp[t], (v2f){djt2, djt2});
      }
    }
    if (done) return;  // uniform across all threads

    // ---- stash this wave's 16 W-columns into its private LDS slab ----
    // (no barrier: wave reads only its own slab; lgkmcnt ordering suffices)
    {
      const bool writer = ((lane >> 4) == (wave & 3));
      const int jl = lane & 15;
      if (writer) {
#pragma unroll
        for (int t = 0; t < 16; ++t)
          Wst[wave][t][jl] = lowhalf ? Wp[t].x : Wp[t].y;
      }
    }

    // ---- rank-16 update: A[r][c] += SW[r][t] * W[c][t] ----
    // W columns via wave-uniform b128 reads of the stash (HW broadcast).
#pragma unroll
    for (int t = 0; t < 16; ++t) {
      const float4 q0 = *(const float4*)&Wst[wave][t][0];
      const float4 q1 = *(const float4*)&Wst[wave][t][4];
      const float4 q2 = *(const float4*)&Wst[wave][t][8];
      const float4 q3 = *(const float4*)&Wst[wave][t][12];
      const v2f w0d = {SWp[t].x, SWp[t].x};
      const v2f w1d = {SWp[t].y, SWp[t].y};
      const v2f c01 = {q0.x, q0.y}, c23 = {q0.z, q0.w};
      const v2f c45 = {q1.x, q1.y}, c67 = {q1.z, q1.w};
      const v2f c89 = {q2.x, q2.y}, cab = {q2.z, q2.w};
      const v2f ccd = {q3.x, q3.y}, cef = {q3.z, q3.w};
      pk_fma_vv(A2r0[0], w0d, c01); pk_fma_vv(A2r1[0], w1d, c01);
      pk_fma_vv(A2r0[1], w0d, c23); pk_fma_vv(A2r1[1], w1d, c23);
      pk_fma_vv(A2r0[2], w0d, c45); pk_fma_vv(A2r1[2], w1d, c45);
      pk_fma_vv(A2r0[3], w0d, c67); pk_fma_vv(A2r1[3], w1d, c67);
      pk_fma_vv(A2r0[4], w0d, c89); pk_fma_vv(A2r1[4], w1d, c89);
      pk_fma_vv(A2r0[5], w0d, cab); pk_fma_vv(A2r1[5], w1d, cab);
      pk_fma_vv(A2r0[6], w0d, ccd); pk_fma_vv(A2r1[6], w1d, ccd);
      pk_fma_vv(A2r0[7], w0d, cef); pk_fma_vv(A2r1[7], w1d, cef);
    }
    // No trailing barrier: next block's LDS writes sit behind its own
    // barriers; this block's cross-wave LDS reads completed before bar3,
    // and Wst is strictly wave-private.
  }
}

extern "C" void kernel_launch(void* const* d_in, const int* in_sizes, int n_in,
                              void* d_out, int out_size, void* d_ws,
                              size_t ws_size, hipStream_t stream) {
  const float* P = (const float*)d_in[0];  // (512, 128) row-major fp32
  const float* u = (const float*)d_in[1];  // (128,) fp32
  float* out = (float*)d_out;              // 65536 cond_probs + 128 positions
  hipLaunchKernelGGL(slater_scan_kernel, dim3(1), dim3(NTHREADS), 0, stream,
                     P, u, out);
}